// Round 1
// baseline (184.300 us; speedup 1.0000x reference)
//
#include <hip/hip_runtime.h>
#include <math.h>

// CompetingRisks: B=4096, D=128, R=2. One wave64 per (r,b) task.
// Phase 1: P_j = b1_j + dot(z_b, w1[j][2:130])  (ODE-invariant hidden preact)
// Phase 2: dopri5 scalar ODE, f-eval = wave-parallel 260-dot + softplus.

#define B_ 4096
#define D_ 128
#define R_ 2
#define IN_ 130
#define HID_ 260
#define MAXSTEPS_ 16
#define H0_ 0.05f
#define RTOL_ 1e-3f
#define ATOL_ 1e-3f

__device__ __forceinline__ float wave_sum64(float v) {
    // butterfly: every lane ends with the full 64-lane sum (state stays wave-uniform)
    v += __shfl_xor(v, 32, 64);
    v += __shfl_xor(v, 16, 64);
    v += __shfl_xor(v, 8, 64);
    v += __shfl_xor(v, 4, 64);
    v += __shfl_xor(v, 2, 64);
    v += __shfl_xor(v, 1, 64);
    return v;
}

__device__ __forceinline__ float softplus_f(float x) {
    // jax.nn.softplus = logaddexp(x,0) = max(x,0) + log1p(exp(-|x|))
    return fmaxf(x, 0.0f) + log1pf(expf(-fabsf(x)));
}

__global__ __launch_bounds__(256) void cr_kernel(
    const float* __restrict__ z, const float* __restrict__ t_eval,
    const float* __restrict__ w1, const float* __restrict__ b1,
    const float* __restrict__ w2, const float* __restrict__ b2,
    float* __restrict__ out)
{
    const int wave = (blockIdx.x << 2) + (threadIdx.x >> 6);
    const int lane = threadIdx.x & 63;
    const int r = wave & 1;        // waves for same b adjacent -> z_b L1 reuse
    const int b = wave >> 1;

    const float te = t_eval[b];

    // ---- Phase 1: per-lane hidden units j = lane + 64*i ----
    float P[5], A[5], C[5], W[5];
    const float* w1r = w1 + r * HID_ * IN_;
    const float* zb  = z + b * D_;
#pragma unroll
    for (int i = 0; i < 5; ++i) {
        const int j = lane + (i << 6);
        if (j < HID_) {
            const float* row = w1r + j * IN_;
            A[i] = row[0];
            C[i] = row[1];
            float acc = b1[r * HID_ + j];
            // row+2 is 8-byte aligned (130*j+2 even) -> float2 loads ok
            const float2* rz = (const float2*)(row + 2);
            const float2* zz = (const float2*)zb;
#pragma unroll 8
            for (int k = 0; k < D_ / 2; ++k) {
                float2 a2 = rz[k];
                float2 z2 = zz[k];
                acc = fmaf(a2.x, z2.x, acc);
                acc = fmaf(a2.y, z2.y, acc);
            }
            P[i] = acc;
            W[i] = w2[r * HID_ + j];
        } else {
            A[i] = 0.f; C[i] = 0.f; P[i] = 0.f; W[i] = 0.f;
        }
    }
    const float b2r = b2[r];

    // ---- f-eval: softplus( sum_j W_j * relu(P_j + tt*A_j + y*C_j) + b2 ) * te ----
    auto feval = [&](float t1, float y) -> float {
        const float tt = t1 * te;
        float dot = 0.f;
#pragma unroll
        for (int i = 0; i < 5; ++i) {
            float hv = fmaf(tt, A[i], fmaf(y, C[i], P[i]));
            dot = fmaf(W[i], fmaxf(hv, 0.f), dot);
        }
        dot = wave_sum64(dot);
        return softplus_f(dot + b2r) * te;
    };

    // ---- Phase 2: dopri5, exact fp32 replication of the reference ----
    const float t1f = 1.0f;
    float t = 0.f, y = 0.f, h = H0_;
    float fy = feval(0.f, 0.f);
    bool done = false;
    for (int s = 0; s < MAXSTEPS_ && !done; ++s) {
        h = fminf(h, t1f - t);
        const float k1 = fy;
        const float k2 = feval(t + 0.2f * h, y + h * (0.2f * k1));
        const float k3 = feval(t + 0.3f * h, y + h * (3.f/40.f * k1 + 9.f/40.f * k2));
        const float k4 = feval(t + 0.8f * h, y + h * (44.f/45.f * k1 - 56.f/15.f * k2 + 32.f/9.f * k3));
        const float k5 = feval(t + 8.f/9.f * h,
            y + h * (19372.f/6561.f * k1 - 25360.f/2187.f * k2 + 64448.f/6561.f * k3 - 212.f/729.f * k4));
        const float k6 = feval(t + h,
            y + h * (9017.f/3168.f * k1 - 355.f/33.f * k2 + 46732.f/5247.f * k3 + 49.f/176.f * k4 - 5103.f/18656.f * k5));
        const float y5 = y + h * (35.f/384.f * k1 + 500.f/1113.f * k3 + 125.f/192.f * k4
                                  - 2187.f/6784.f * k5 + 11.f/84.f * k6);
        const float k7 = feval(t + h, y5);
        const float err = h * (71.f/57600.f * k1 - 71.f/16695.f * k3 + 71.f/1920.f * k4
                               - 17253.f/339200.f * k5 + 22.f/525.f * k6 - 1.f/40.f * k7);
        const float scale = ATOL_ + RTOL_ * fmaxf(fabsf(y), fabsf(y5));
        const float ratio = err / scale;
        const float en = sqrtf(ratio * ratio);
        const bool accept = (en <= 1.0f);
        const float fac = fminf(fmaxf(0.9f * powf(fmaxf(en, 1e-10f), -0.2f), 0.2f), 10.f);
        if (accept) { t = t + h; y = y5; fy = k7; }
        h = h * fac;
        done = (t >= t1f - 1e-9f);
    }

    const float yT = y;
    const float hazf = feval(1.0f, yT);
    const float t_rec = (te != 0.f) ? (1.f / te) : 0.f;

    if (lane == 0) {
        // haz: [R,1,B] at offset 0
        out[r * B_ + b] = t_rec * hazf;
        // chf: [R,B,2,1] at offset R*B
        const int base = R_ * B_ + (r * B_ + b) * 2;
        out[base + 0] = 0.f;
        out[base + 1] = yT;
    }
}

extern "C" void kernel_launch(void* const* d_in, const int* in_sizes, int n_in,
                              void* d_out, int out_size, void* d_ws, size_t ws_size,
                              hipStream_t stream) {
    const float* z      = (const float*)d_in[0];
    const float* t_eval = (const float*)d_in[1];
    const float* w1     = (const float*)d_in[2];
    const float* b1     = (const float*)d_in[3];
    const float* w2     = (const float*)d_in[4];
    const float* b2     = (const float*)d_in[5];
    float* out = (float*)d_out;

    const int n_tasks = R_ * B_;            // 8192 waves
    dim3 grid(n_tasks / 4), block(256);     // 4 waves/block
    hipLaunchKernelGGL(cr_kernel, grid, block, 0, stream,
                       z, t_eval, w1, b1, w2, b2, out);
}

// Round 2
// 159.486 us; speedup vs baseline: 1.1556x; 1.1556x over previous
//
#include <hip/hip_runtime.h>
#include <math.h>

// CompetingRisks: B=4096, D=128, R=2. 4 tasks per wave, 16 lanes per task.
// Phase 1: P_j = b1_j + dot(z_b, w1[j][2:130])  (ODE-invariant hidden preact)
// Phase 2: dopri5 scalar ODE; f-eval = 17 fused units/lane + 4-op DPP reduce.

#define B_ 4096
#define R_ 2
#define D_ 128
#define IN_ 130
#define HID_ 260
#define MAXSTEPS_ 16
#define H0_ 0.05f
#define RTOL_ 1e-3f
#define ATOL_ 1e-3f
#define NU_ 17   // 16*16 + 4 = 260 hidden units per 16-lane group

// Sum across a 16-lane row; result uniform in all 16 lanes. Pure DPP (VALU).
__device__ __forceinline__ float dpp_add16(float v) {
    int y;
    y = __builtin_amdgcn_update_dpp(0, __float_as_int(v), 0xB1, 0xF, 0xF, false);  // quad_perm [1,0,3,2] = xor1
    v += __int_as_float(y);
    y = __builtin_amdgcn_update_dpp(0, __float_as_int(v), 0x4E, 0xF, 0xF, false);  // quad_perm [2,3,0,1] = xor2
    v += __int_as_float(y);
    y = __builtin_amdgcn_update_dpp(0, __float_as_int(v), 0x124, 0xF, 0xF, false); // row_ror:4
    v += __int_as_float(y);
    y = __builtin_amdgcn_update_dpp(0, __float_as_int(v), 0x128, 0xF, 0xF, false); // row_ror:8
    v += __int_as_float(y);
    return v;
}

// softplus(x) = max(x,0) + log1p(exp(-|x|)) via native v_exp_f32 / v_log_f32
__device__ __forceinline__ float softplus_fast(float x) {
    const float q  = exp2f(-1.4426950408889634f * fabsf(x));
    const float lg = 0.6931471805599453f * log2f(1.0f + q);
    return fmaxf(x, 0.0f) + lg;
}

__global__ __launch_bounds__(256) void cr_kernel(
    const float* __restrict__ z, const float* __restrict__ t_eval,
    const float* __restrict__ w1, const float* __restrict__ b1,
    const float* __restrict__ w2, const float* __restrict__ b2,
    float* __restrict__ out)
{
    const int sub = threadIdx.x & 15;                 // lane within 16-lane group
    const int T   = blockIdx.x * 16 + (threadIdx.x >> 4);  // task id, r-major
    const int r   = T >> 12;                          // all 16 tasks in a block share r
    const int b   = T & (B_ - 1);

    const float te = t_eval[b];

    // ---- Phase 1: per-lane hidden units j = sub + 16*i ----
    float P[NU_], A[NU_], C[NU_], W[NU_];
    const float* w1r = w1 + r * HID_ * IN_;
    const float* zb  = z + b * D_;
#pragma unroll
    for (int i = 0; i < NU_; ++i) {
        const int j = sub + (i << 4);
        if (j < HID_) {                               // only i==16 is conditional (sub<4)
            const float* row = w1r + j * IN_;
            A[i] = row[0];
            C[i] = row[1];
            float a0 = b1[r * HID_ + j], a1 = 0.f;
            const float2* rw = (const float2*)(row + 2);   // 8B aligned (130j+2 even)
            const float2* zz = (const float2*)zb;
#pragma unroll 8
            for (int k = 0; k < D_ / 2; ++k) {
                float2 wv = rw[k], zv = zz[k];
                a0 = fmaf(wv.x, zv.x, a0);
                a1 = fmaf(wv.y, zv.y, a1);
            }
            P[i] = a0 + a1;
            W[i] = w2[r * HID_ + j];
        } else {
            P[i] = A[i] = C[i] = W[i] = 0.f;
        }
    }
    const float b2r = b2[r];

    // ---- f-eval: softplus( sum_j W_j*relu(P_j + tt*A_j + y*C_j) + b2 ) * te ----
    auto feval = [&](float t1, float yv) -> float {
        const float tt = t1 * te;
        float d0 = 0.f, d1 = 0.f;
#pragma unroll
        for (int i = 0; i < NU_; ++i) {
            const float hv = fmaf(tt, A[i], fmaf(yv, C[i], P[i]));
            if (i & 1) d1 = fmaf(W[i], fmaxf(hv, 0.f), d1);
            else       d0 = fmaf(W[i], fmaxf(hv, 0.f), d0);
        }
        const float dot = dpp_add16(d0 + d1);
        return softplus_fast(dot + b2r) * te;
    };

    // ---- Phase 2: dopri5, fp32 replication; groups masked, wave-uniform exit ----
    float t = 0.f, y = 0.f, h = H0_;
    float fy = feval(0.f, 0.f);
    bool done = false;
    for (int s = 0; s < MAXSTEPS_; ++s) {
        if (__ballot(!done) == 0ULL) break;           // all 4 groups finished
        h = fminf(h, 1.0f - t);
        const float k1 = fy;
        const float k2 = feval(t + 0.2f * h, y + h * (0.2f * k1));
        const float k3 = feval(t + 0.3f * h, y + h * (3.f/40.f * k1 + 9.f/40.f * k2));
        const float k4 = feval(t + 0.8f * h, y + h * (44.f/45.f * k1 - 56.f/15.f * k2 + 32.f/9.f * k3));
        const float k5 = feval(t + 8.f/9.f * h,
            y + h * (19372.f/6561.f * k1 - 25360.f/2187.f * k2 + 64448.f/6561.f * k3 - 212.f/729.f * k4));
        const float k6 = feval(t + h,
            y + h * (9017.f/3168.f * k1 - 355.f/33.f * k2 + 46732.f/5247.f * k3 + 49.f/176.f * k4 - 5103.f/18656.f * k5));
        const float y5 = y + h * (35.f/384.f * k1 + 500.f/1113.f * k3 + 125.f/192.f * k4
                                  - 2187.f/6784.f * k5 + 11.f/84.f * k6);
        const float k7 = feval(t + h, y5);
        const float err = h * (71.f/57600.f * k1 - 71.f/16695.f * k3 + 71.f/1920.f * k4
                               - 17253.f/339200.f * k5 + 22.f/525.f * k6 - 1.f/40.f * k7);
        const float scale = ATOL_ + RTOL_ * fmaxf(fabsf(y), fabsf(y5));
        const float ratio = err / scale;
        const float en = sqrtf(ratio * ratio);        // mimic ref's sqrt(mean(sq))
        const bool accept = (en <= 1.0f) && (!done);
        // fac: native exp2/log2 (only perturbs h, never the accept test)
        const float fac = fminf(fmaxf(0.9f * exp2f(-0.2f * log2f(fmaxf(en, 1e-10f))), 0.2f), 10.f);
        const float t_n = accept ? t + h : t;
        y  = accept ? y5 : y;
        fy = accept ? k7 : fy;
        h  = done ? h : h * fac;                      // old done, per reference
        t  = t_n;
        done = done || (t >= 1.0f - 1e-9f);
    }

    const float yT = y;
    const float hazf = feval(1.0f, yT);
    const float t_rec = (te != 0.f) ? (1.f / te) : 0.f;

    if (sub == 0) {
        out[r * B_ + b] = t_rec * hazf;               // haz: [R,1,B]
        const int base = R_ * B_ + (r * B_ + b) * 2;  // chf: [R,B,2,1]
        out[base + 0] = 0.f;
        out[base + 1] = yT;
    }
}

extern "C" void kernel_launch(void* const* d_in, const int* in_sizes, int n_in,
                              void* d_out, int out_size, void* d_ws, size_t ws_size,
                              hipStream_t stream) {
    const float* z      = (const float*)d_in[0];
    const float* t_eval = (const float*)d_in[1];
    const float* w1     = (const float*)d_in[2];
    const float* b1     = (const float*)d_in[3];
    const float* w2     = (const float*)d_in[4];
    const float* b2     = (const float*)d_in[5];
    float* out = (float*)d_out;

    const int n_tasks = R_ * B_;                // 8192 tasks, 16 per block
    dim3 grid(n_tasks / 16), block(256);        // 512 blocks, 4 waves each
    hipLaunchKernelGGL(cr_kernel, grid, block, 0, stream,
                       z, t_eval, w1, b1, w2, b2, out);
}